// Round 3
// baseline (763.795 us; speedup 1.0000x reference)
//
#include <hip/hip_runtime.h>
#include <cstdint>
#include <cstddef>

typedef __bf16 bf16_t;
typedef __bf16 bf16x8 __attribute__((ext_vector_type(8)));
typedef float  f32x4  __attribute__((ext_vector_type(4)));
typedef unsigned int uint32x4 __attribute__((ext_vector_type(4)));

#define DEV_INLINE __device__ __forceinline__

constexpr int Bsz = 4, Ssz = 2048, HID = 1024, FAC = 256, NH = 16, DKc = 64;
constexpr int Mrows = Bsz * Ssz; // 8192
constexpr float QSCALE = 0.18033688011112042f; // (1/sqrt(64)) * log2(e)

struct Ptr8 { const float* p[8]; };
struct Ptr3 { const float* p[3]; };

DEV_INLINE float fast_exp2(float x) {
#if __has_builtin(__builtin_amdgcn_exp2f)
  return __builtin_amdgcn_exp2f(x);
#else
  return exp2f(x);
#endif
}

// async global->LDS, 16 B per lane. LDS dest is wave-uniform base + lane*16.
DEV_INLINE void async16(const void* g, void* l) {
  __builtin_amdgcn_global_load_lds((const __attribute__((address_space(1))) void*)g,
                                   (__attribute__((address_space(3))) void*)l, 16, 0, 0);
}

// ---------------- weight transpose + cast: W[K,N] f32 -> Wt[N,K] bf16 ----------------
__global__ __launch_bounds__(256) void k_prep_w(Ptr8 s, bf16_t* wpt, bf16_t* wtt) {
  const int z = blockIdx.z;
  const int K = (z < 4) ? HID : FAC;
  const int N = (z < 4) ? FAC : HID;
  if ((int)(blockIdx.x * 32) >= N || (int)(blockIdx.y * 32) >= K) return;
  __shared__ float t[32][33];
  const float* src = s.p[z];
  bf16_t* dst = (z < 4) ? (wpt + (size_t)z * FAC * HID) : (wtt + (size_t)(z - 4) * FAC * HID);
  const int tx = threadIdx.x & 31, ty = threadIdx.x >> 5;
  const int kb = blockIdx.y * 32, nb = blockIdx.x * 32;
#pragma unroll
  for (int j = 0; j < 4; ++j)
    t[ty + j * 8][tx] = src[(size_t)(kb + ty + j * 8) * N + nb + tx];
  __syncthreads();
#pragma unroll
  for (int j = 0; j < 4; ++j)
    dst[(size_t)(nb + ty + j * 8) * K + kb + tx] = (bf16_t)t[tx][ty + j * 8];
}

// ---------------- bias pack + mask->float rowmul + mask->bf16 row ----------------
__global__ __launch_bounds__(256) void k_pack_bias(Ptr8 s, const int* __restrict__ mask,
                                                   float* bp, float* bt, float* mf, bf16_t* mb) {
  const int tid = threadIdx.x;
  for (int i = tid; i < 4 * FAC; i += 256) bp[i] = s.p[i >> 8][i & 255];
  for (int i = tid; i < 4 * HID; i += 256) bt[i] = s.p[4 + (i >> 10)][i & 1023];
  for (int i = tid; i < Bsz * Ssz; i += 256) {
    const float m = (mask[i] != 0) ? 1.f : 0.f;
    mf[i] = m;
    mb[i] = (bf16_t)m;
  }
}

// ---------------- V transpose: src[b*S+s][h*64+d] -> dst[(b*NH+h)*64+d][s] ----------------
__global__ __launch_bounds__(256) void k_tv(const bf16_t* __restrict__ src, bf16_t* __restrict__ dst) {
  constexpr int LDT = 72;
  __shared__ __align__(16) bf16_t T[64 * LDT];
  const int st = blockIdx.x, h = blockIdx.y, b = blockIdx.z;
  const int tid = threadIdx.x;
  const int sr = tid >> 3, sc8 = (tid & 7) * 8;
  const size_t g0 = (size_t)(b * Ssz + st * 64 + sr) * HID + h * DKc + sc8;
  *(uint32x4*)(T + sr * LDT + sc8) = *(const uint32x4*)(src + g0);
  *(uint32x4*)(T + (sr + 32) * LDT + sc8) = *(const uint32x4*)(src + g0 + (size_t)32 * HID);
  __syncthreads();
  union { bf16_t e[8]; uint32x4 u; } o0, o1;
#pragma unroll
  for (int j = 0; j < 8; ++j) {
    o0.e[j] = T[(sc8 + j) * LDT + sr];
    o1.e[j] = T[(sc8 + j) * LDT + sr + 32];
  }
  const size_t d0 = ((size_t)(b * NH + h) * DKc + sr) * Ssz + st * 64 + sc8;
  *(uint32x4*)(dst + d0) = o0.u;
  *(uint32x4*)(dst + d0 + (size_t)32 * Ssz) = o1.u;
}

// ---------------- bf16 MFMA GEMM: C[M,N] = act(A[M,K] @ Bt[N,K]^T + bias) * scale [* rowmul] ----
// 128x128 tile, BK=32, 4 waves 2x2, 16x16x32 MFMA. B staged via global_load_lds (LDT=32);
// A likewise when bf16, or fp32->bf16 cast-fused manual staging (LDT=40) when CAST_A.
template <int CAST_A, int ACT, int RM, typename OUT_T>
__global__ __launch_bounds__(256) void k_gemm(Ptr3 Asrc,
                                              const bf16_t* __restrict__ Aall,
                                              const bf16_t* __restrict__ Btall,
                                              const float* __restrict__ biasAll,
                                              OUT_T* __restrict__ Call,
                                              OUT_T* __restrict__ C2,
                                              const float* __restrict__ rowmul,
                                              int N, int K,
                                              long long Az, long long Bz, long long Cz, int biasz,
                                              float sc0, float sc1, float sc2) {
  constexpr int LDTA = CAST_A ? 40 : 32;
  __shared__ __align__(16) bf16_t As[128 * LDTA];
  __shared__ __align__(16) bf16_t Bs[128 * 32];

  const int z = blockIdx.z;
  const bf16_t* Bt = Btall + (size_t)z * Bz;
  const float* bias = biasAll + (size_t)z * biasz;
  OUT_T* C = (z == 2 && C2) ? C2 : (Call + (size_t)z * Cz);
  const float scale = (z == 0) ? sc0 : ((z == 1) ? sc1 : sc2);

  const int tid = threadIdx.x;
  const int lane = tid & 63, wave = tid >> 6;
  const int quad = lane >> 4, l16 = lane & 15;
  const int wr = wave >> 1, wc = wave & 1;
  const int m0 = blockIdx.y * 128, n0 = blockIdx.x * 128;

  // async staging map: element index i*8, i = call*256 + wave*64 + lane -> row=i>>2, kc=i&3
  const int arow = wave * 16 + (lane >> 2), akc = (lane & 3) * 8;
  const bf16_t* gB0 = Bt + (size_t)(n0 + arow) * K + akc;
  const bf16_t* gB1 = gB0 + (size_t)64 * K;
  bf16_t* lB0 = Bs + wave * 512;
  bf16_t* lB1 = Bs + 2048 + wave * 512;

  // A async (bf16 path)
  const bf16_t* gA0 = nullptr; const bf16_t* gA1 = nullptr;
  bf16_t* lA0 = As + wave * 512;
  bf16_t* lA1 = As + 2048 + wave * 512;
  // A cast path (fp32 source)
  const float* gAf = nullptr;
  bf16_t* lAc = nullptr;
  if (CAST_A) {
    const int crow = tid >> 1, chalf = (tid & 1) * 16;
    gAf = Asrc.p[z] + (size_t)(m0 + crow) * K + chalf;
    lAc = As + crow * LDTA + chalf;
  } else {
    const bf16_t* A = Aall + (size_t)z * Az;
    gA0 = A + (size_t)(m0 + arow) * K + akc;
    gA1 = gA0 + (size_t)64 * K;
  }

  f32x4 acc[4][4] = {};

  for (int k0 = 0; k0 < K; k0 += 32) {
    // stage
    async16(gB0 + k0, lB0);
    async16(gB1 + k0, lB1);
    if (CAST_A) {
      f32x4 x0 = *(const f32x4*)(gAf + k0);
      f32x4 x1 = *(const f32x4*)(gAf + k0 + 4);
      f32x4 x2 = *(const f32x4*)(gAf + k0 + 8);
      f32x4 x3 = *(const f32x4*)(gAf + k0 + 12);
      union { bf16_t h[16]; uint32x4 u[2]; } o;
#pragma unroll
      for (int j = 0; j < 4; ++j) {
        o.h[j] = (bf16_t)x0[j]; o.h[4 + j] = (bf16_t)x1[j];
        o.h[8 + j] = (bf16_t)x2[j]; o.h[12 + j] = (bf16_t)x3[j];
      }
      *(uint32x4*)lAc = o.u[0];
      *(uint32x4*)(lAc + 8) = o.u[1];
    } else {
      async16(gA0 + k0, lA0);
      async16(gA1 + k0, lA1);
    }
    __syncthreads();

    bf16x8 af[4], bfr[4];
#pragma unroll
    for (int i = 0; i < 4; ++i)
      af[i] = *(const bf16x8*)(As + (wr * 64 + i * 16 + l16) * LDTA + quad * 8);
#pragma unroll
    for (int i = 0; i < 4; ++i)
      bfr[i] = *(const bf16x8*)(Bs + (wc * 64 + i * 16 + l16) * 32 + quad * 8);
#pragma unroll
    for (int mi = 0; mi < 4; ++mi)
#pragma unroll
      for (int ni = 0; ni < 4; ++ni)
        acc[mi][ni] = __builtin_amdgcn_mfma_f32_16x16x32_bf16(af[mi], bfr[ni], acc[mi][ni], 0, 0, 0);
    if (k0 + 32 < K) __syncthreads();
  }

#pragma unroll
  for (int mi = 0; mi < 4; ++mi) {
    const int rbase = m0 + wr * 64 + mi * 16 + quad * 4;
    float rmv[4] = {1.f, 1.f, 1.f, 1.f};
    if (RM && z == 2) {
#pragma unroll
      for (int r = 0; r < 4; ++r) rmv[r] = rowmul[rbase + r];
    }
#pragma unroll
    for (int ni = 0; ni < 4; ++ni) {
      const int col = n0 + wc * 64 + ni * 16 + l16;
      const float bv = bias[col];
#pragma unroll
      for (int r = 0; r < 4; ++r) {
        float y = acc[mi][ni][r] + bv;
        if (ACT == 1) y = (y > 0.f) ? y : 0.2f * y;
        y *= scale * rmv[r];
        C[(size_t)(rbase + r) * N + col] = (OUT_T)y;
      }
    }
  }
}

// ---------------- flash attention v3 ----------------
// S^T via swapped MFMA operands with remapped K rows (key = koff[ks] + 8*quad + r) so each
// lane's exp2'd C-regs pack directly into its PV A-fragment: no LDS for P, no cross-lane moves.
// Mask: V rows pre-zeroed (numerator); denominator via extra MFMA tile w/ mask-row B-operand.
__global__ __launch_bounds__(256, 4) void k_attn(const bf16_t* __restrict__ qkv,
                                                 const bf16_t* __restrict__ mb,
                                                 bf16_t* __restrict__ cv) {
  constexpr int LDA = 76;
  __shared__ __align__(16) bf16_t Ks[2][64 * LDA];
  __shared__ __align__(16) bf16_t Vt[2][64 * LDA];

  const int qt = blockIdx.x, h = blockIdx.y, b = blockIdx.z;
  const bf16_t* qp = qkv;
  const bf16_t* kp = qkv + (size_t)Mrows * HID;
  const bf16_t* vtp = qkv + 2 * (size_t)Mrows * HID + (size_t)(b * NH + h) * DKc * Ssz;

  const int tid = threadIdx.x;
  const int lane = tid & 63, wave = tid >> 6;
  const int quad = lane >> 4, l16 = lane & 15;
  const int sr = tid >> 3, sc8 = (tid & 7) * 8;

  // Q fragments direct from global (B-operand; n = q-local = l16 within the wave's 16 rows)
  const size_t qrow = (size_t)(b * Ssz + qt * 64 + wave * 16 + l16) * HID + h * DKc + quad * 8;
  const bf16x8 aq0 = *(const bf16x8*)(qp + qrow);
  const bf16x8 aq1 = *(const bf16x8*)(qp + qrow + 32);

  const bf16_t* kg0 = kp + (size_t)(b * Ssz + sr) * HID + h * DKc + sc8;
  const bf16_t* kg1 = kg0 + (size_t)32 * HID;
  const bf16_t* vg0 = vtp + (size_t)sr * Ssz + sc8;
  const bf16_t* vg1 = vg0 + (size_t)32 * Ssz;
  const bf16_t* mbp = mb + (size_t)b * Ssz + quad * 8;

  // prologue: stage tile 0 into buffer 0
  {
    uint32x4 a = *(const uint32x4*)kg0;
    uint32x4 b2 = *(const uint32x4*)kg1;
    uint32x4 c = *(const uint32x4*)vg0;
    uint32x4 d = *(const uint32x4*)vg1;
    *(uint32x4*)(Ks[0] + sr * LDA + sc8) = a;
    *(uint32x4*)(Ks[0] + (sr + 32) * LDA + sc8) = b2;
    *(uint32x4*)(Vt[0] + sr * LDA + sc8) = c;
    *(uint32x4*)(Vt[0] + (sr + 32) * LDA + sc8) = d;
  }
  __syncthreads();

  const int krow = 8 * (l16 >> 2) + (l16 & 3); // remapped K-row base for A-operand
  f32x4 acc[4] = {};
  f32x4 dacc = {};
  const bf16x8 zfrag = {};

  for (int kt = 0; kt < 32; ++kt) {
    const int cur = kt & 1, nxt = cur ^ 1;
    const int ktn = (kt < 31) ? kt + 1 : 31;
    uint32x4 rk0 = *(const uint32x4*)(kg0 + (size_t)ktn * 64 * HID);
    uint32x4 rk1 = *(const uint32x4*)(kg1 + (size_t)ktn * 64 * HID);
    uint32x4 rv0 = *(const uint32x4*)(vg0 + ktn * 64);
    uint32x4 rv1 = *(const uint32x4*)(vg1 + ktn * 64);

    // QK^T (S^T): A = K rows (remapped), B = Q. Lane (l16,quad) chunk ks reg r -> key koff+8*quad+r.
    uint32_t pk[8];
    constexpr int koff[4] = {0, 4, 32, 36};
#pragma unroll
    for (int ks = 0; ks < 4; ++ks) {
      const bf16_t* kr = Ks[cur] + (krow + koff[ks]) * LDA + quad * 8;
      bf16x8 a0 = *(const bf16x8*)kr;
      bf16x8 a1 = *(const bf16x8*)(kr + 32);
      f32x4 c = {};
      c = __builtin_amdgcn_mfma_f32_16x16x32_bf16(a0, aq0, c, 0, 0, 0);
      c = __builtin_amdgcn_mfma_f32_16x16x32_bf16(a1, aq1, c, 0, 0, 0);
      union { bf16_t h[2]; uint32_t u; } p01, p23;
      p01.h[0] = (bf16_t)fast_exp2(c[0]);
      p01.h[1] = (bf16_t)fast_exp2(c[1]);
      p23.h[0] = (bf16_t)fast_exp2(c[2]);
      p23.h[1] = (bf16_t)fast_exp2(c[3]);
      pk[ks * 2] = p01.u;
      pk[ks * 2 + 1] = p23.u;
    }
    union { uint32x4 u; bf16x8 h; } ap0u, ap1u;
    ap0u.u = uint32x4{pk[0], pk[1], pk[2], pk[3]}; // keys 8*quad + 0..7   (kk=0)
    ap1u.u = uint32x4{pk[4], pk[5], pk[6], pk[7]}; // keys 32 + 8*quad + 0..7 (kk=1)

    // denominator tile: B-operand = mask row, nonzero only on l16==0 lanes
    bf16x8 mr0 = *(const bf16x8*)(mbp + kt * 64);
    bf16x8 mr1 = *(const bf16x8*)(mbp + kt * 64 + 32);
    if (l16 != 0) { mr0 = zfrag; mr1 = zfrag; }
    dacc = __builtin_amdgcn_mfma_f32_16x16x32_bf16(ap0u.h, mr0, dacc, 0, 0, 0);
    dacc = __builtin_amdgcn_mfma_f32_16x16x32_bf16(ap1u.h, mr1, dacc, 0, 0, 0);

    // P @ V (V rows are pre-masked to zero)
#pragma unroll
    for (int d = 0; d < 4; ++d) {
      const bf16_t* vr = Vt[cur] + (d * 16 + l16) * LDA + quad * 8;
      bf16x8 bv0 = *(const bf16x8*)vr;
      bf16x8 bv1 = *(const bf16x8*)(vr + 32);
      acc[d] = __builtin_amdgcn_mfma_f32_16x16x32_bf16(ap0u.h, bv0, acc[d], 0, 0, 0);
      acc[d] = __builtin_amdgcn_mfma_f32_16x16x32_bf16(ap1u.h, bv1, acc[d], 0, 0, 0);
    }

    *(uint32x4*)(Ks[nxt] + sr * LDA + sc8) = rk0;
    *(uint32x4*)(Ks[nxt] + (sr + 32) * LDA + sc8) = rk1;
    *(uint32x4*)(Vt[nxt] + sr * LDA + sc8) = rv0;
    *(uint32x4*)(Vt[nxt] + (sr + 32) * LDA + sc8) = rv1;
    __syncthreads();
  }

  const size_t obase = (size_t)(b * Ssz + qt * 64 + wave * 16 + quad * 4) * HID + h * DKc + l16;
#pragma unroll
  for (int r = 0; r < 4; ++r) {
    const float denom = __shfl(dacc[r], lane & 48, 64); // col 0 lives on lane quad*16
    const float rl = 1.f / denom;
#pragma unroll
    for (int d = 0; d < 4; ++d)
      cv[obase + (size_t)r * HID + d * 16] = (bf16_t)(acc[d][r] * rl);
  }
}

// ---------------- host ----------------
extern "C" void kernel_launch(void* const* d_in, const int* in_sizes, int n_in,
                              void* d_out, int out_size, void* d_ws, size_t ws_size,
                              hipStream_t stream) {
  (void)in_sizes; (void)n_in; (void)out_size; (void)ws_size;
  const float* q_in = (const float*)d_in[0];
  const float* k_in = (const float*)d_in[1];
  const float* v_in = (const float*)d_in[2];
  const int* mask = (const int*)d_in[3];

  bf16_t* XB = (bf16_t*)d_ws;                          // 3 slots [8192,1024] bf16: q, k, V^T
  bf16_t* H3 = XB + (size_t)3 * Mrows * HID;           // 3 x [8192,256] bf16
  bf16_t* CV = H3 + (size_t)3 * Mrows * FAC;           // [8192,1024] bf16 (masked V, then attn out)
  bf16_t* WPT = CV + (size_t)Mrows * HID;              // 4 x [256,1024] bf16
  bf16_t* WTT = WPT + (size_t)4 * FAC * HID;           // 4 x [1024,256] bf16
  float* BP = (float*)(WTT + (size_t)4 * FAC * HID);   // 4 x 256 f32
  float* BT = BP + 4 * FAC;                            // 4 x 1024 f32
  float* MF = BT + 4 * HID;                            // [8192] f32 mask rowmul
  bf16_t* MB = (bf16_t*)(MF + Mrows);                  // [8192] bf16 mask row
  bf16_t* VTg = XB + 2 * (size_t)Mrows * HID;

  Ptr8 w;
  w.p[0] = (const float*)d_in[4];  w.p[1] = (const float*)d_in[8];
  w.p[2] = (const float*)d_in[12]; w.p[3] = (const float*)d_in[16];
  w.p[4] = (const float*)d_in[6];  w.p[5] = (const float*)d_in[10];
  w.p[6] = (const float*)d_in[14]; w.p[7] = (const float*)d_in[18];
  hipLaunchKernelGGL(k_prep_w, dim3(32, 32, 8), dim3(256), 0, stream, w, WPT, WTT);

  Ptr8 bs;
  bs.p[0] = (const float*)d_in[5];  bs.p[1] = (const float*)d_in[9];
  bs.p[2] = (const float*)d_in[13]; bs.p[3] = (const float*)d_in[17];
  bs.p[4] = (const float*)d_in[7];  bs.p[5] = (const float*)d_in[11];
  bs.p[6] = (const float*)d_in[15]; bs.p[7] = (const float*)d_in[19];
  hipLaunchKernelGGL(k_pack_bias, dim3(1), dim3(256), 0, stream, bs, mask, BP, BT, MF, MB);

  Ptr3 xs; xs.p[0] = q_in; xs.p[1] = k_in; xs.p[2] = v_in;
  Ptr3 nullp; nullp.p[0] = nullp.p[1] = nullp.p[2] = nullptr;

  // proj q,k,v: fp32 A (cast fused) @ WPT^T + b -> leaky -> H3
  hipLaunchKernelGGL((k_gemm<1, 1, 0, bf16_t>), dim3(FAC / 128, Mrows / 128, 3), dim3(256), 0, stream,
                     xs, (const bf16_t*)nullptr, WPT, BP, H3, (bf16_t*)nullptr, (const float*)nullptr,
                     FAC, HID, 0LL, (long long)FAC * HID, (long long)Mrows * FAC, FAC,
                     1.f, 1.f, 1.f);

  // tran q,k,v: H3 @ WTT^T + b -> q,k into XB; v (mask-multiplied rows) into CV
  hipLaunchKernelGGL((k_gemm<0, 0, 1, bf16_t>), dim3(HID / 128, Mrows / 128, 3), dim3(256), 0, stream,
                     nullp, H3, WTT, BT, XB, CV, MF,
                     HID, FAC, (long long)Mrows * FAC, (long long)FAC * HID, (long long)Mrows * HID, HID,
                     QSCALE, 1.f, 1.f);

  // transpose masked V: CV -> VTg ([b,h,d,s])
  hipLaunchKernelGGL(k_tv, dim3(Ssz / 64, NH, Bsz), dim3(256), 0, stream, CV, VTg);

  // attention -> CV
  hipLaunchKernelGGL(k_attn, dim3(Ssz / 64, NH, Bsz), dim3(256), 0, stream, XB, MB, CV);

  // proj o: CV @ WPT[o]^T + b -> leaky -> H3[0]
  hipLaunchKernelGGL((k_gemm<0, 1, 0, bf16_t>), dim3(FAC / 128, Mrows / 128, 1), dim3(256), 0, stream,
                     nullp, CV, WPT + (size_t)3 * FAC * HID, BP + 3 * FAC, H3, (bf16_t*)nullptr,
                     (const float*)nullptr, FAC, HID, 0LL, 0LL, 0LL, 0, 1.f, 1.f, 1.f);

  // tran o: H3 @ WTT[o]^T + b -> d_out (fp32)
  hipLaunchKernelGGL((k_gemm<0, 0, 0, float>), dim3(HID / 128, Mrows / 128, 1), dim3(256), 0, stream,
                     nullp, H3, WTT + (size_t)3 * FAC * HID, BT + 3 * HID, (float*)d_out, (float*)nullptr,
                     (const float*)nullptr, HID, FAC, 0LL, 0LL, 0LL, 0, 1.f, 1.f, 1.f);
}

// Round 4
// 378.913 us; speedup vs baseline: 2.0158x; 2.0158x over previous
//
#include <hip/hip_runtime.h>
#include <cstdint>
#include <cstddef>

typedef __bf16 bf16_t;
typedef __bf16 bf16x8 __attribute__((ext_vector_type(8)));
typedef float  f32x4  __attribute__((ext_vector_type(4)));
typedef unsigned int uint32x4 __attribute__((ext_vector_type(4)));

#define DEV_INLINE __device__ __forceinline__

constexpr int Bsz = 4, Ssz = 2048, HID = 1024, FAC = 256, NH = 16, DKc = 64;
constexpr int Mrows = Bsz * Ssz; // 8192
constexpr float QSCALE = 0.18033688011112042f; // (1/sqrt(64)) * log2(e)

struct Ptr8 { const float* p[8]; };
struct Ptr3 { const float* p[3]; };

DEV_INLINE float fast_exp2(float x) {
#if __has_builtin(__builtin_amdgcn_exp2f)
  return __builtin_amdgcn_exp2f(x);
#else
  return exp2f(x);
#endif
}

// async global->LDS, 16 B per lane. LDS dest is wave-uniform base + lane*16.
DEV_INLINE void async16(const void* g, void* l) {
  __builtin_amdgcn_global_load_lds((const __attribute__((address_space(1))) void*)g,
                                   (__attribute__((address_space(3))) void*)l, 16, 0, 0);
}

// bank swizzle for [64][64] bf16 tiles staged by global_load_lds:
// LDS[row][c'] holds logical col16 (c' ^ SW(row)). Readers XOR too.
DEV_INLINE int SW(int r) { return (r & 3) | ((r >> 1) & 4); }

// ---------------- weight transpose + cast: W[K,N] f32 -> Wt[N,K] bf16 ----------------
__global__ __launch_bounds__(256) void k_prep_w(Ptr8 s, bf16_t* wpt, bf16_t* wtt) {
  const int z = blockIdx.z;
  const int K = (z < 4) ? HID : FAC;
  const int N = (z < 4) ? FAC : HID;
  if ((int)(blockIdx.x * 32) >= N || (int)(blockIdx.y * 32) >= K) return;
  __shared__ float t[32][33];
  const float* src = s.p[z];
  bf16_t* dst = (z < 4) ? (wpt + (size_t)z * FAC * HID) : (wtt + (size_t)(z - 4) * FAC * HID);
  const int tx = threadIdx.x & 31, ty = threadIdx.x >> 5;
  const int kb = blockIdx.y * 32, nb = blockIdx.x * 32;
#pragma unroll
  for (int j = 0; j < 4; ++j)
    t[ty + j * 8][tx] = src[(size_t)(kb + ty + j * 8) * N + nb + tx];
  __syncthreads();
#pragma unroll
  for (int j = 0; j < 4; ++j)
    dst[(size_t)(nb + ty + j * 8) * K + kb + tx] = (bf16_t)t[tx][ty + j * 8];
}

// ---------------- bias pack + mask->float rowmul + mask->bf16 row ----------------
__global__ __launch_bounds__(256) void k_pack_bias(Ptr8 s, const int* __restrict__ mask,
                                                   float* bp, float* bt, float* mf, bf16_t* mb) {
  const int tid = threadIdx.x;
  for (int i = tid; i < 4 * FAC; i += 256) bp[i] = s.p[i >> 8][i & 255];
  for (int i = tid; i < 4 * HID; i += 256) bt[i] = s.p[4 + (i >> 10)][i & 1023];
  for (int i = tid; i < Bsz * Ssz; i += 256) {
    const float m = (mask[i] != 0) ? 1.f : 0.f;
    mf[i] = m;
    mb[i] = (bf16_t)m;
  }
}

// ---------------- V transpose: src[b*S+s][h*64+d] -> dst[(b*NH+h)*64+d][s] ----------------
__global__ __launch_bounds__(256) void k_tv(const bf16_t* __restrict__ src, bf16_t* __restrict__ dst) {
  constexpr int LDT = 72;
  __shared__ __align__(16) bf16_t T[64 * LDT];
  const int st = blockIdx.x, h = blockIdx.y, b = blockIdx.z;
  const int tid = threadIdx.x;
  const int sr = tid >> 3, sc8 = (tid & 7) * 8;
  const size_t g0 = (size_t)(b * Ssz + st * 64 + sr) * HID + h * DKc + sc8;
  *(uint32x4*)(T + sr * LDT + sc8) = *(const uint32x4*)(src + g0);
  *(uint32x4*)(T + (sr + 32) * LDT + sc8) = *(const uint32x4*)(src + g0 + (size_t)32 * HID);
  __syncthreads();
  union { bf16_t e[8]; uint32x4 u; } o0, o1;
#pragma unroll
  for (int j = 0; j < 8; ++j) {
    o0.e[j] = T[(sc8 + j) * LDT + sr];
    o1.e[j] = T[(sc8 + j) * LDT + sr + 32];
  }
  const size_t d0 = ((size_t)(b * NH + h) * DKc + sr) * Ssz + st * 64 + sc8;
  *(uint32x4*)(dst + d0) = o0.u;
  *(uint32x4*)(dst + d0 + (size_t)32 * Ssz) = o1.u;
}

// ---------------- bf16 MFMA GEMM: C[M,N] = act(A[M,K] @ Bt[N,K]^T + bias) * scale [* rowmul] ----
template <int CAST_A, int ACT, int RM, typename OUT_T>
__global__ __launch_bounds__(256) void k_gemm(Ptr3 Asrc,
                                              const bf16_t* __restrict__ Aall,
                                              const bf16_t* __restrict__ Btall,
                                              const float* __restrict__ biasAll,
                                              OUT_T* __restrict__ Call,
                                              OUT_T* __restrict__ C2,
                                              const float* __restrict__ rowmul,
                                              int N, int K,
                                              long long Az, long long Bz, long long Cz, int biasz,
                                              float sc0, float sc1, float sc2) {
  constexpr int LDTA = CAST_A ? 40 : 32;
  __shared__ __align__(16) bf16_t As[128 * LDTA];
  __shared__ __align__(16) bf16_t Bs[128 * 32];

  const int z = blockIdx.z;
  const bf16_t* Bt = Btall + (size_t)z * Bz;
  const float* bias = biasAll + (size_t)z * biasz;
  OUT_T* C = (z == 2 && C2) ? C2 : (Call + (size_t)z * Cz);
  const float scale = (z == 0) ? sc0 : ((z == 1) ? sc1 : sc2);

  const int tid = threadIdx.x;
  const int lane = tid & 63, wave = tid >> 6;
  const int quad = lane >> 4, l16 = lane & 15;
  const int wr = wave >> 1, wc = wave & 1;
  const int m0 = blockIdx.y * 128, n0 = blockIdx.x * 128;

  const int arow = wave * 16 + (lane >> 2), akc = (lane & 3) * 8;
  const bf16_t* gB0 = Bt + (size_t)(n0 + arow) * K + akc;
  const bf16_t* gB1 = gB0 + (size_t)64 * K;
  bf16_t* lB0 = Bs + wave * 512;
  bf16_t* lB1 = Bs + 2048 + wave * 512;

  const bf16_t* gA0 = nullptr; const bf16_t* gA1 = nullptr;
  bf16_t* lA0 = As + wave * 512;
  bf16_t* lA1 = As + 2048 + wave * 512;
  const float* gAf = nullptr;
  bf16_t* lAc = nullptr;
  if (CAST_A) {
    const int crow = tid >> 1, chalf = (tid & 1) * 16;
    gAf = Asrc.p[z] + (size_t)(m0 + crow) * K + chalf;
    lAc = As + crow * LDTA + chalf;
  } else {
    const bf16_t* A = Aall + (size_t)z * Az;
    gA0 = A + (size_t)(m0 + arow) * K + akc;
    gA1 = gA0 + (size_t)64 * K;
  }

  f32x4 acc[4][4] = {};

  for (int k0 = 0; k0 < K; k0 += 32) {
    async16(gB0 + k0, lB0);
    async16(gB1 + k0, lB1);
    if (CAST_A) {
      f32x4 x0 = *(const f32x4*)(gAf + k0);
      f32x4 x1 = *(const f32x4*)(gAf + k0 + 4);
      f32x4 x2 = *(const f32x4*)(gAf + k0 + 8);
      f32x4 x3 = *(const f32x4*)(gAf + k0 + 12);
      union { bf16_t h[16]; uint32x4 u[2]; } o;
#pragma unroll
      for (int j = 0; j < 4; ++j) {
        o.h[j] = (bf16_t)x0[j]; o.h[4 + j] = (bf16_t)x1[j];
        o.h[8 + j] = (bf16_t)x2[j]; o.h[12 + j] = (bf16_t)x3[j];
      }
      *(uint32x4*)lAc = o.u[0];
      *(uint32x4*)(lAc + 8) = o.u[1];
    } else {
      async16(gA0 + k0, lA0);
      async16(gA1 + k0, lA1);
    }
    __syncthreads();

    bf16x8 af[4], bfr[4];
#pragma unroll
    for (int i = 0; i < 4; ++i)
      af[i] = *(const bf16x8*)(As + (wr * 64 + i * 16 + l16) * LDTA + quad * 8);
#pragma unroll
    for (int i = 0; i < 4; ++i)
      bfr[i] = *(const bf16x8*)(Bs + (wc * 64 + i * 16 + l16) * 32 + quad * 8);
#pragma unroll
    for (int mi = 0; mi < 4; ++mi)
#pragma unroll
      for (int ni = 0; ni < 4; ++ni)
        acc[mi][ni] = __builtin_amdgcn_mfma_f32_16x16x32_bf16(af[mi], bfr[ni], acc[mi][ni], 0, 0, 0);
    if (k0 + 32 < K) __syncthreads();
  }

#pragma unroll
  for (int mi = 0; mi < 4; ++mi) {
    const int rbase = m0 + wr * 64 + mi * 16 + quad * 4;
    float rmv[4] = {1.f, 1.f, 1.f, 1.f};
    if (RM && z == 2) {
#pragma unroll
      for (int r = 0; r < 4; ++r) rmv[r] = rowmul[rbase + r];
    }
#pragma unroll
    for (int ni = 0; ni < 4; ++ni) {
      const int col = n0 + wc * 64 + ni * 16 + l16;
      const float bv = bias[col];
#pragma unroll
      for (int r = 0; r < 4; ++r) {
        float y = acc[mi][ni][r] + bv;
        if (ACT == 1) y = (y > 0.f) ? y : 0.2f * y;
        y *= scale * rmv[r];
        C[(size_t)(rbase + r) * N + col] = (OUT_T)y;
      }
    }
  }
}

// ---------------- flash attention v4 ----------------
// 128 q-rows/block (2 groups of 64), 4 waves. K/V double-buffered [64][64] LDS tiles staged
// by global_load_lds DMA with bank-swizzled source addresses (no VGPR prefetch to sink,
// __syncthreads drains vmcnt). Mask in LDS (prologue). Softmax fused in registers (v3 scheme):
// S^T via swapped operands + krow remap so exp2'd C-regs ARE the PV A-fragment.
__global__ __launch_bounds__(256, 4) void k_attn(const bf16_t* __restrict__ qkv,
                                                 const bf16_t* __restrict__ mb,
                                                 bf16_t* __restrict__ cv) {
  __shared__ __align__(16) bf16_t Ks[2][64 * 64];
  __shared__ __align__(16) bf16_t Vt[2][64 * 64];
  __shared__ __align__(16) bf16_t Ml[Ssz];

  const int qt = blockIdx.x, h = blockIdx.y, b = blockIdx.z;
  const bf16_t* qp = qkv;
  const bf16_t* kp = qkv + (size_t)Mrows * HID;
  const bf16_t* vtp = qkv + 2 * (size_t)Mrows * HID + (size_t)(b * NH + h) * DKc * Ssz;

  const int tid = threadIdx.x;
  const int lane = tid & 63, wave = tid >> 6;
  const int quad = lane >> 4, l16 = lane & 15;

  // DMA staging map: wave w issues instrs j=2w,2w+1 per tile; instr j covers rows 8j..8j+7.
  // lane i -> row 8j + (i>>3), dest col16' = i&7, source logical col16 = (i&7) ^ SW(row).
  const int r0 = wave * 16 + (lane >> 3);
  const int r1 = r0 + 8;
  const int c0 = ((lane & 7) ^ SW(r0)) * 8;
  const int c1 = ((lane & 7) ^ SW(r1)) * 8;
  const int ldsOff = wave * 1024; // elements: instr j dest = buf + j*512
  const bf16_t* kgA = kp + (size_t)(b * Ssz + r0) * HID + h * DKc + c0;
  const bf16_t* kgB = kp + (size_t)(b * Ssz + r1) * HID + h * DKc + c1;
  const bf16_t* vgA = vtp + (size_t)r0 * Ssz + c0;
  const bf16_t* vgB = vtp + (size_t)r1 * Ssz + c1;

  // prologue: mask row -> LDS; tile 0 -> buffer 0
  *(uint32x4*)(Ml + tid * 8) = *(const uint32x4*)(mb + (size_t)b * Ssz + tid * 8);
  async16(kgA, Ks[0] + ldsOff);
  async16(kgB, Ks[0] + ldsOff + 512);
  async16(vgA, Vt[0] + ldsOff);
  async16(vgB, Vt[0] + ldsOff + 512);

  // Q fragments (B-operand), 2 groups of 64 q-rows
  bf16x8 aq0[2], aq1[2];
#pragma unroll
  for (int g = 0; g < 2; ++g) {
    const size_t qrow = (size_t)(b * Ssz + qt * 128 + g * 64 + wave * 16 + l16) * HID + h * DKc + quad * 8;
    aq0[g] = *(const bf16x8*)(qp + qrow);
    aq1[g] = *(const bf16x8*)(qp + qrow + 32);
  }
  __syncthreads();

  const int krow = 8 * (l16 >> 2) + (l16 & 3);
  f32x4 acc[2][4] = {};
  f32x4 dacc[2] = {};
  const bf16x8 zfrag = {};

  for (int kt = 0; kt < 32; ++kt) {
    const int cur = kt & 1, nxt = cur ^ 1;
    if (kt < 31) { // DMA next tile into the other buffer (readers of it passed last barrier)
      const size_t ko = (size_t)(kt + 1) * 64 * HID;
      const int vo = (kt + 1) * 64;
      async16(kgA + ko, Ks[nxt] + ldsOff);
      async16(kgB + ko, Ks[nxt] + ldsOff + 512);
      async16(vgA + vo, Vt[nxt] + ldsOff);
      async16(vgB + vo, Vt[nxt] + ldsOff + 512);
    }

    // QK^T (S^T): A = K rows (remapped), B = Q. exp2 -> packed PV A-fragments, per group.
    uint32_t pk[2][8];
    constexpr int koff[4] = {0, 4, 32, 36};
#pragma unroll
    for (int ks = 0; ks < 4; ++ks) {
      const int row = krow + koff[ks];
      const int sw = SW(row);
      bf16x8 a0 = *(const bf16x8*)(Ks[cur] + row * 64 + (quad ^ sw) * 8);
      bf16x8 a1 = *(const bf16x8*)(Ks[cur] + row * 64 + ((quad + 4) ^ sw) * 8);
#pragma unroll
      for (int g = 0; g < 2; ++g) {
        f32x4 c = {};
        c = __builtin_amdgcn_mfma_f32_16x16x32_bf16(a0, aq0[g], c, 0, 0, 0);
        c = __builtin_amdgcn_mfma_f32_16x16x32_bf16(a1, aq1[g], c, 0, 0, 0);
        union { bf16_t h[2]; uint32_t u; } p01, p23;
        p01.h[0] = (bf16_t)fast_exp2(c[0]);
        p01.h[1] = (bf16_t)fast_exp2(c[1]);
        p23.h[0] = (bf16_t)fast_exp2(c[2]);
        p23.h[1] = (bf16_t)fast_exp2(c[3]);
        pk[g][ks * 2] = p01.u;
        pk[g][ks * 2 + 1] = p23.u;
      }
    }
    union { uint32x4 u; bf16x8 h; } ap0[2], ap1[2];
#pragma unroll
    for (int g = 0; g < 2; ++g) {
      ap0[g].u = uint32x4{pk[g][0], pk[g][1], pk[g][2], pk[g][3]};
      ap1[g].u = uint32x4{pk[g][4], pk[g][5], pk[g][6], pk[g][7]};
    }

    // denominator: B-operand = mask row from LDS (broadcast), nonzero only on l16==0 lanes
    bf16x8 mr0 = *(const bf16x8*)(Ml + kt * 64 + quad * 8);
    bf16x8 mr1 = *(const bf16x8*)(Ml + kt * 64 + 32 + quad * 8);
    if (l16 != 0) { mr0 = zfrag; mr1 = zfrag; }
#pragma unroll
    for (int g = 0; g < 2; ++g) {
      dacc[g] = __builtin_amdgcn_mfma_f32_16x16x32_bf16(ap0[g].h, mr0, dacc[g], 0, 0, 0);
      dacc[g] = __builtin_amdgcn_mfma_f32_16x16x32_bf16(ap1[g].h, mr1, dacc[g], 0, 0, 0);
    }

    // P @ V (V rows pre-masked to zero)
#pragma unroll
    for (int d = 0; d < 4; ++d) {
      const int row = d * 16 + l16;
      const int sw = SW(row);
      bf16x8 bv0 = *(const bf16x8*)(Vt[cur] + row * 64 + (quad ^ sw) * 8);
      bf16x8 bv1 = *(const bf16x8*)(Vt[cur] + row * 64 + ((quad + 4) ^ sw) * 8);
#pragma unroll
      for (int g = 0; g < 2; ++g) {
        acc[g][d] = __builtin_amdgcn_mfma_f32_16x16x32_bf16(ap0[g].h, bv0, acc[g][d], 0, 0, 0);
        acc[g][d] = __builtin_amdgcn_mfma_f32_16x16x32_bf16(ap1[g].h, bv1, acc[g][d], 0, 0, 0);
      }
    }

    __syncthreads(); // drains DMA (vmcnt) + everyone done reading [cur]
  }

#pragma unroll
  for (int g = 0; g < 2; ++g) {
    const size_t obase = (size_t)(b * Ssz + qt * 128 + g * 64 + wave * 16 + quad * 4) * HID + h * DKc + l16;
#pragma unroll
    for (int r = 0; r < 4; ++r) {
      const float denom = __shfl(dacc[g][r], lane & 48, 64); // col 0 lives on lane quad*16
      const float rl = 1.f / denom;
#pragma unroll
      for (int d = 0; d < 4; ++d)
        cv[obase + (size_t)r * HID + d * 16] = (bf16_t)(acc[g][d][r] * rl);
    }
  }
}

// ---------------- host ----------------
extern "C" void kernel_launch(void* const* d_in, const int* in_sizes, int n_in,
                              void* d_out, int out_size, void* d_ws, size_t ws_size,
                              hipStream_t stream) {
  (void)in_sizes; (void)n_in; (void)out_size; (void)ws_size;
  const float* q_in = (const float*)d_in[0];
  const float* k_in = (const float*)d_in[1];
  const float* v_in = (const float*)d_in[2];
  const int* mask = (const int*)d_in[3];

  bf16_t* XB = (bf16_t*)d_ws;                          // 3 slots [8192,1024] bf16: q, k, V^T
  bf16_t* H3 = XB + (size_t)3 * Mrows * HID;           // 3 x [8192,256] bf16
  bf16_t* CV = H3 + (size_t)3 * Mrows * FAC;           // [8192,1024] bf16 (masked V, then attn out)
  bf16_t* WPT = CV + (size_t)Mrows * HID;              // 4 x [256,1024] bf16
  bf16_t* WTT = WPT + (size_t)4 * FAC * HID;           // 4 x [1024,256] bf16
  float* BP = (float*)(WTT + (size_t)4 * FAC * HID);   // 4 x 256 f32
  float* BT = BP + 4 * FAC;                            // 4 x 1024 f32
  float* MF = BT + 4 * HID;                            // [8192] f32 mask rowmul
  bf16_t* MB = (bf16_t*)(MF + Mrows);                  // [8192] bf16 mask row
  bf16_t* VTg = XB + 2 * (size_t)Mrows * HID;

  Ptr8 w;
  w.p[0] = (const float*)d_in[4];  w.p[1] = (const float*)d_in[8];
  w.p[2] = (const float*)d_in[12]; w.p[3] = (const float*)d_in[16];
  w.p[4] = (const float*)d_in[6];  w.p[5] = (const float*)d_in[10];
  w.p[6] = (const float*)d_in[14]; w.p[7] = (const float*)d_in[18];
  hipLaunchKernelGGL(k_prep_w, dim3(32, 32, 8), dim3(256), 0, stream, w, WPT, WTT);

  Ptr8 bs;
  bs.p[0] = (const float*)d_in[5];  bs.p[1] = (const float*)d_in[9];
  bs.p[2] = (const float*)d_in[13]; bs.p[3] = (const float*)d_in[17];
  bs.p[4] = (const float*)d_in[7];  bs.p[5] = (const float*)d_in[11];
  bs.p[6] = (const float*)d_in[15]; bs.p[7] = (const float*)d_in[19];
  hipLaunchKernelGGL(k_pack_bias, dim3(1), dim3(256), 0, stream, bs, mask, BP, BT, MF, MB);

  Ptr3 xs; xs.p[0] = q_in; xs.p[1] = k_in; xs.p[2] = v_in;
  Ptr3 nullp; nullp.p[0] = nullp.p[1] = nullp.p[2] = nullptr;

  // proj q,k,v: fp32 A (cast fused) @ WPT^T + b -> leaky -> H3
  hipLaunchKernelGGL((k_gemm<1, 1, 0, bf16_t>), dim3(FAC / 128, Mrows / 128, 3), dim3(256), 0, stream,
                     xs, (const bf16_t*)nullptr, WPT, BP, H3, (bf16_t*)nullptr, (const float*)nullptr,
                     FAC, HID, 0LL, (long long)FAC * HID, (long long)Mrows * FAC, FAC,
                     1.f, 1.f, 1.f);

  // tran q,k,v: H3 @ WTT^T + b -> q,k into XB; v (mask-multiplied rows) into CV
  hipLaunchKernelGGL((k_gemm<0, 0, 1, bf16_t>), dim3(HID / 128, Mrows / 128, 3), dim3(256), 0, stream,
                     nullp, H3, WTT, BT, XB, CV, MF,
                     HID, FAC, (long long)Mrows * FAC, (long long)FAC * HID, (long long)Mrows * HID, HID,
                     QSCALE, 1.f, 1.f);

  // transpose masked V: CV -> VTg ([b,h,d,s])
  hipLaunchKernelGGL(k_tv, dim3(Ssz / 64, NH, Bsz), dim3(256), 0, stream, CV, VTg);

  // attention -> CV (128 q-rows per block)
  hipLaunchKernelGGL(k_attn, dim3(Ssz / 128, NH, Bsz), dim3(256), 0, stream, XB, MB, CV);

  // proj o: CV @ WPT[o]^T + b -> leaky -> H3[0]
  hipLaunchKernelGGL((k_gemm<0, 1, 0, bf16_t>), dim3(FAC / 128, Mrows / 128, 1), dim3(256), 0, stream,
                     nullp, CV, WPT + (size_t)3 * FAC * HID, BP + 3 * FAC, H3, (bf16_t*)nullptr,
                     (const float*)nullptr, FAC, HID, 0LL, 0LL, 0LL, 0, 1.f, 1.f, 1.f);

  // tran o: H3 @ WTT[o]^T + b -> d_out (fp32)
  hipLaunchKernelGGL((k_gemm<0, 0, 0, float>), dim3(HID / 128, Mrows / 128, 1), dim3(256), 0, stream,
                     nullp, H3, WTT + (size_t)3 * FAC * HID, BT + 3 * HID, (float*)d_out, (float*)nullptr,
                     (const float*)nullptr, HID, FAC, 0LL, 0LL, 0LL, 0, 1.f, 1.f, 1.f);
}

// Round 5
// 353.594 us; speedup vs baseline: 2.1601x; 1.0716x over previous
//
#include <hip/hip_runtime.h>
#include <cstdint>
#include <cstddef>

typedef __bf16 bf16_t;
typedef __bf16 bf16x8 __attribute__((ext_vector_type(8)));
typedef float  f32x4  __attribute__((ext_vector_type(4)));
typedef unsigned int uint32x4 __attribute__((ext_vector_type(4)));

#define DEV_INLINE __device__ __forceinline__

constexpr int Bsz = 4, Ssz = 2048, HID = 1024, FAC = 256, NH = 16, DKc = 64;
constexpr int Mrows = Bsz * Ssz; // 8192
constexpr float QSCALE = 0.18033688011112042f; // (1/sqrt(64)) * log2(e)

struct Ptr8 { const float* p[8]; };
struct Ptr3 { const float* p[3]; };

DEV_INLINE float fast_exp2(float x) {
#if __has_builtin(__builtin_amdgcn_exp2f)
  return __builtin_amdgcn_exp2f(x);
#else
  return exp2f(x);
#endif
}

// async global->LDS, 16 B per lane. LDS dest is wave-uniform base + lane*16.
DEV_INLINE void async16(const void* g, void* l) {
  __builtin_amdgcn_global_load_lds((const __attribute__((address_space(1))) void*)g,
                                   (__attribute__((address_space(3))) void*)l, 16, 0, 0);
}

// bank swizzle for [64][64] bf16 tiles staged by global_load_lds:
// LDS[row][c'] holds logical col16 (c' ^ SW(row)). Readers XOR too.
DEV_INLINE int SW(int r) { return (r & 3) | ((r >> 1) & 4); }

// ---------------- weight transpose + cast: W[K,N] f32 -> Wt[N,K] bf16 ----------------
__global__ __launch_bounds__(256) void k_prep_w(Ptr8 s, bf16_t* wpt, bf16_t* wtt) {
  const int z = blockIdx.z;
  const int K = (z < 4) ? HID : FAC;
  const int N = (z < 4) ? FAC : HID;
  if ((int)(blockIdx.x * 32) >= N || (int)(blockIdx.y * 32) >= K) return;
  __shared__ float t[32][33];
  const float* src = s.p[z];
  bf16_t* dst = (z < 4) ? (wpt + (size_t)z * FAC * HID) : (wtt + (size_t)(z - 4) * FAC * HID);
  const int tx = threadIdx.x & 31, ty = threadIdx.x >> 5;
  const int kb = blockIdx.y * 32, nb = blockIdx.x * 32;
#pragma unroll
  for (int j = 0; j < 4; ++j)
    t[ty + j * 8][tx] = src[(size_t)(kb + ty + j * 8) * N + nb + tx];
  __syncthreads();
#pragma unroll
  for (int j = 0; j < 4; ++j)
    dst[(size_t)(nb + ty + j * 8) * K + kb + tx] = (bf16_t)t[tx][ty + j * 8];
}

// ---------------- bias pack + mask->float rowmul + mask->bf16 row (parallel) ----------------
__global__ __launch_bounds__(256) void k_pack_bias(Ptr8 s, const int* __restrict__ mask,
                                                   float* bp, float* bt, float* mf, bf16_t* mb) {
  const int i = blockIdx.x * 256 + threadIdx.x;
  if (i < 4 * FAC) bp[i] = s.p[i >> 8][i & 255];
  if (i < 4 * HID) bt[i] = s.p[4 + (i >> 10)][i & 1023];
  if (i < Bsz * Ssz) {
    const float m = (mask[i] != 0) ? 1.f : 0.f;
    mf[i] = m;
    mb[i] = (bf16_t)m;
  }
}

// ---------------- V transpose: src[b*S+s][h*64+d] -> dst[(b*NH+h)*64+d][s] ----------------
__global__ __launch_bounds__(256) void k_tv(const bf16_t* __restrict__ src, bf16_t* __restrict__ dst) {
  constexpr int LDT = 72;
  __shared__ __align__(16) bf16_t T[64 * LDT];
  const int st = blockIdx.x, h = blockIdx.y, b = blockIdx.z;
  const int tid = threadIdx.x;
  const int sr = tid >> 3, sc8 = (tid & 7) * 8;
  const size_t g0 = (size_t)(b * Ssz + st * 64 + sr) * HID + h * DKc + sc8;
  *(uint32x4*)(T + sr * LDT + sc8) = *(const uint32x4*)(src + g0);
  *(uint32x4*)(T + (sr + 32) * LDT + sc8) = *(const uint32x4*)(src + g0 + (size_t)32 * HID);
  __syncthreads();
  union { bf16_t e[8]; uint32x4 u; } o0, o1;
#pragma unroll
  for (int j = 0; j < 8; ++j) {
    o0.e[j] = T[(sc8 + j) * LDT + sr];
    o1.e[j] = T[(sc8 + j) * LDT + sr + 32];
  }
  const size_t d0 = ((size_t)(b * NH + h) * DKc + sr) * Ssz + st * 64 + sc8;
  *(uint32x4*)(dst + d0) = o0.u;
  *(uint32x4*)(dst + d0 + (size_t)32 * Ssz) = o1.u;
}

// ---------------- proj GEMM: C[M,256] = leaky(A[M,K] @ Bt[256,K]^T + bias) ----------------
// 64x128 tile, BK=32, 4 waves (each 64x32), double-buffered LDS, ONE barrier per K-iter.
// DMA + A-prefetch issued immediately after the barrier so compute covers the latency.
template <int CAST_A, typename OUT_T>
__global__ __launch_bounds__(256) void k_gemmP(Ptr3 Asrc,
                                               const bf16_t* __restrict__ Aall,
                                               const bf16_t* __restrict__ Bt_,
                                               const float* __restrict__ biasAll,
                                               OUT_T* __restrict__ Call,
                                               int K,
                                               long long Az, long long Bz, long long Cz, int biasz) {
  constexpr int LDTA = CAST_A ? 40 : 32;
  __shared__ __align__(16) bf16_t As[2][64 * LDTA];
  __shared__ __align__(16) bf16_t Bs[2][128 * 32];

  const int z = blockIdx.z;
  const bf16_t* Bt = Bt_ + (size_t)z * Bz;
  const float* bias = biasAll + (size_t)z * biasz;
  OUT_T* C = Call + (size_t)z * Cz;

  const int tid = threadIdx.x;
  const int lane = tid & 63, wave = tid >> 6;
  const int quad = lane >> 4, l16 = lane & 15;
  const int m0 = blockIdx.y * 64, n0 = blockIdx.x * 128;

  // async staging map (per wave): lane i covers element (wave*64+i)*8 -> row wave*16+(i>>2), col (i&3)*8
  const int arow = wave * 16 + (lane >> 2), akc = (lane & 3) * 8;
  const bf16_t* gB0 = Bt + (size_t)(n0 + arow) * K + akc;
  const bf16_t* gB1 = gB0 + (size_t)64 * K;

  const float* gAf = nullptr;
  const bf16_t* gA = nullptr;
  const int crow = tid >> 2, chalf = (tid & 3) * 8;
  if (CAST_A) gAf = Asrc.p[z] + (size_t)(m0 + crow) * K + chalf;
  else        gA  = Aall + (size_t)z * Az + (size_t)(m0 + arow) * K + akc;

  // prologue: stage k0=0 into buffer 0
  async16(gB0, Bs[0] + wave * 512);
  async16(gB1, Bs[0] + 2048 + wave * 512);
  if (CAST_A) {
    f32x4 x0 = *(const f32x4*)gAf;
    f32x4 x1 = *(const f32x4*)(gAf + 4);
    union { bf16_t h[8]; uint32x4 u; } o;
#pragma unroll
    for (int j = 0; j < 4; ++j) { o.h[j] = (bf16_t)x0[j]; o.h[4 + j] = (bf16_t)x1[j]; }
    *(uint32x4*)(As[0] + crow * LDTA + chalf) = o.u;
  } else {
    async16(gA, As[0] + wave * 512);
  }

  f32x4 acc[4][2] = {};
  const int nk = K / 32;

  for (int it = 0; it < nk; ++it) {
    const int cur = it & 1, nxt = cur ^ 1;
    __syncthreads(); // staging for [cur] complete (drains DMA + LDS writes)

    f32x4 xa, xb;
    const int k1 = (it + 1) * 32;
    if (it + 1 < nk) {
      async16(gB0 + k1, Bs[nxt] + wave * 512);
      async16(gB1 + k1, Bs[nxt] + 2048 + wave * 512);
      if (CAST_A) {
        xa = *(const f32x4*)(gAf + k1);
        xb = *(const f32x4*)(gAf + k1 + 4);
      } else {
        async16(gA + k1, As[nxt] + wave * 512);
      }
    }

    bf16x8 af[4], bfr[2];
#pragma unroll
    for (int i = 0; i < 4; ++i)
      af[i] = *(const bf16x8*)(As[cur] + (i * 16 + l16) * LDTA + quad * 8);
#pragma unroll
    for (int i = 0; i < 2; ++i)
      bfr[i] = *(const bf16x8*)(Bs[cur] + (wave * 32 + i * 16 + l16) * 32 + quad * 8);
#pragma unroll
    for (int mi = 0; mi < 4; ++mi)
#pragma unroll
      for (int ni = 0; ni < 2; ++ni)
        acc[mi][ni] = __builtin_amdgcn_mfma_f32_16x16x32_bf16(af[mi], bfr[ni], acc[mi][ni], 0, 0, 0);

    if (CAST_A && it + 1 < nk) {
      union { bf16_t h[8]; uint32x4 u; } o;
#pragma unroll
      for (int j = 0; j < 4; ++j) { o.h[j] = (bf16_t)xa[j]; o.h[4 + j] = (bf16_t)xb[j]; }
      *(uint32x4*)(As[nxt] + crow * LDTA + chalf) = o.u;
    }
  }

#pragma unroll
  for (int mi = 0; mi < 4; ++mi) {
    const int rbase = m0 + mi * 16 + quad * 4;
#pragma unroll
    for (int ni = 0; ni < 2; ++ni) {
      const int col = n0 + wave * 32 + ni * 16 + l16;
      const float bv = bias[col];
#pragma unroll
      for (int r = 0; r < 4; ++r) {
        float y = acc[mi][ni][r] + bv;
        y = (y > 0.f) ? y : 0.2f * y;
        C[(size_t)(rbase + r) * FAC + col] = (OUT_T)y;
      }
    }
  }
}

// ---------------- bf16 MFMA GEMM (tran): C[M,N] = (A[M,K] @ Bt[N,K]^T + bias) * scale [* rowmul] -
template <int ACT, int RM, typename OUT_T>
__global__ __launch_bounds__(256) void k_gemm(const bf16_t* __restrict__ Aall,
                                              const bf16_t* __restrict__ Btall,
                                              const float* __restrict__ biasAll,
                                              OUT_T* __restrict__ Call,
                                              OUT_T* __restrict__ C2,
                                              const float* __restrict__ rowmul,
                                              int N, int K,
                                              long long Az, long long Bz, long long Cz, int biasz,
                                              float sc0, float sc1, float sc2) {
  __shared__ __align__(16) bf16_t As[128 * 32];
  __shared__ __align__(16) bf16_t Bs[128 * 32];

  const int z = blockIdx.z;
  const bf16_t* Bt = Btall + (size_t)z * Bz;
  const float* bias = biasAll + (size_t)z * biasz;
  OUT_T* C = (z == 2 && C2) ? C2 : (Call + (size_t)z * Cz);
  const float scale = (z == 0) ? sc0 : ((z == 1) ? sc1 : sc2);

  const int tid = threadIdx.x;
  const int lane = tid & 63, wave = tid >> 6;
  const int quad = lane >> 4, l16 = lane & 15;
  const int wr = wave >> 1, wc = wave & 1;
  const int m0 = blockIdx.y * 128, n0 = blockIdx.x * 128;

  const int arow = wave * 16 + (lane >> 2), akc = (lane & 3) * 8;
  const bf16_t* gB0 = Bt + (size_t)(n0 + arow) * K + akc;
  const bf16_t* gB1 = gB0 + (size_t)64 * K;
  bf16_t* lB0 = Bs + wave * 512;
  bf16_t* lB1 = Bs + 2048 + wave * 512;

  const bf16_t* A = Aall + (size_t)z * Az;
  const bf16_t* gA0 = A + (size_t)(m0 + arow) * K + akc;
  const bf16_t* gA1 = gA0 + (size_t)64 * K;
  bf16_t* lA0 = As + wave * 512;
  bf16_t* lA1 = As + 2048 + wave * 512;

  f32x4 acc[4][4] = {};

  for (int k0 = 0; k0 < K; k0 += 32) {
    async16(gB0 + k0, lB0);
    async16(gB1 + k0, lB1);
    async16(gA0 + k0, lA0);
    async16(gA1 + k0, lA1);
    __syncthreads();

    bf16x8 af[4], bfr[4];
#pragma unroll
    for (int i = 0; i < 4; ++i)
      af[i] = *(const bf16x8*)(As + (wr * 64 + i * 16 + l16) * 32 + quad * 8);
#pragma unroll
    for (int i = 0; i < 4; ++i)
      bfr[i] = *(const bf16x8*)(Bs + (wc * 64 + i * 16 + l16) * 32 + quad * 8);
#pragma unroll
    for (int mi = 0; mi < 4; ++mi)
#pragma unroll
      for (int ni = 0; ni < 4; ++ni)
        acc[mi][ni] = __builtin_amdgcn_mfma_f32_16x16x32_bf16(af[mi], bfr[ni], acc[mi][ni], 0, 0, 0);
    if (k0 + 32 < K) __syncthreads();
  }

#pragma unroll
  for (int mi = 0; mi < 4; ++mi) {
    const int rbase = m0 + wr * 64 + mi * 16 + quad * 4;
    float rmv[4] = {1.f, 1.f, 1.f, 1.f};
    if (RM && z == 2) {
#pragma unroll
      for (int r = 0; r < 4; ++r) rmv[r] = rowmul[rbase + r];
    }
#pragma unroll
    for (int ni = 0; ni < 4; ++ni) {
      const int col = n0 + wc * 64 + ni * 16 + l16;
      const float bv = bias[col];
#pragma unroll
      for (int r = 0; r < 4; ++r) {
        float y = acc[mi][ni][r] + bv;
        if (ACT == 1) y = (y > 0.f) ? y : 0.2f * y;
        y *= scale * rmv[r];
        C[(size_t)(rbase + r) * N + col] = (OUT_T)y;
      }
    }
  }
}

// ---------------- flash attention v4 (unchanged from round 4) ----------------
__global__ __launch_bounds__(256, 4) void k_attn(const bf16_t* __restrict__ qkv,
                                                 const bf16_t* __restrict__ mb,
                                                 bf16_t* __restrict__ cv) {
  __shared__ __align__(16) bf16_t Ks[2][64 * 64];
  __shared__ __align__(16) bf16_t Vt[2][64 * 64];
  __shared__ __align__(16) bf16_t Ml[Ssz];

  const int qt = blockIdx.x, h = blockIdx.y, b = blockIdx.z;
  const bf16_t* qp = qkv;
  const bf16_t* kp = qkv + (size_t)Mrows * HID;
  const bf16_t* vtp = qkv + 2 * (size_t)Mrows * HID + (size_t)(b * NH + h) * DKc * Ssz;

  const int tid = threadIdx.x;
  const int lane = tid & 63, wave = tid >> 6;
  const int quad = lane >> 4, l16 = lane & 15;

  const int r0 = wave * 16 + (lane >> 3);
  const int r1 = r0 + 8;
  const int c0 = ((lane & 7) ^ SW(r0)) * 8;
  const int c1 = ((lane & 7) ^ SW(r1)) * 8;
  const int ldsOff = wave * 1024;
  const bf16_t* kgA = kp + (size_t)(b * Ssz + r0) * HID + h * DKc + c0;
  const bf16_t* kgB = kp + (size_t)(b * Ssz + r1) * HID + h * DKc + c1;
  const bf16_t* vgA = vtp + (size_t)r0 * Ssz + c0;
  const bf16_t* vgB = vtp + (size_t)r1 * Ssz + c1;

  *(uint32x4*)(Ml + tid * 8) = *(const uint32x4*)(mb + (size_t)b * Ssz + tid * 8);
  async16(kgA, Ks[0] + ldsOff);
  async16(kgB, Ks[0] + ldsOff + 512);
  async16(vgA, Vt[0] + ldsOff);
  async16(vgB, Vt[0] + ldsOff + 512);

  bf16x8 aq0[2], aq1[2];
#pragma unroll
  for (int g = 0; g < 2; ++g) {
    const size_t qrow = (size_t)(b * Ssz + qt * 128 + g * 64 + wave * 16 + l16) * HID + h * DKc + quad * 8;
    aq0[g] = *(const bf16x8*)(qp + qrow);
    aq1[g] = *(const bf16x8*)(qp + qrow + 32);
  }
  __syncthreads();

  const int krow = 8 * (l16 >> 2) + (l16 & 3);
  f32x4 acc[2][4] = {};
  f32x4 dacc[2] = {};
  const bf16x8 zfrag = {};

  for (int kt = 0; kt < 32; ++kt) {
    const int cur = kt & 1, nxt = cur ^ 1;
    if (kt < 31) {
      const size_t ko = (size_t)(kt + 1) * 64 * HID;
      const int vo = (kt + 1) * 64;
      async16(kgA + ko, Ks[nxt] + ldsOff);
      async16(kgB + ko, Ks[nxt] + ldsOff + 512);
      async16(vgA + vo, Vt[nxt] + ldsOff);
      async16(vgB + vo, Vt[nxt] + ldsOff + 512);
    }

    uint32_t pk[2][8];
    constexpr int koff[4] = {0, 4, 32, 36};
#pragma unroll
    for (int ks = 0; ks < 4; ++ks) {
      const int row = krow + koff[ks];
      const int sw = SW(row);
      bf16x8 a0 = *(const bf16x8*)(Ks[cur] + row * 64 + (quad ^ sw) * 8);
      bf16x8 a1 = *(const bf16x8*)(Ks[cur] + row * 64 + ((quad + 4) ^ sw) * 8);
#pragma unroll
      for (int g = 0; g < 2; ++g) {
        f32x4 c = {};
        c = __builtin_amdgcn_mfma_f32_16x16x32_bf16(a0, aq0[g], c, 0, 0, 0);
        c = __builtin_amdgcn_mfma_f32_16x16x32_bf16(a1, aq1[g], c, 0, 0, 0);
        union { bf16_t h[2]; uint32_t u; } p01, p23;
        p01.h[0] = (bf16_t)fast_exp2(c[0]);
        p01.h[1] = (bf16_t)fast_exp2(c[1]);
        p23.h[0] = (bf16_t)fast_exp2(c[2]);
        p23.h[1] = (bf16_t)fast_exp2(c[3]);
        pk[g][ks * 2] = p01.u;
        pk[g][ks * 2 + 1] = p23.u;
      }
    }
    union { uint32x4 u; bf16x8 h; } ap0[2], ap1[2];
#pragma unroll
    for (int g = 0; g < 2; ++g) {
      ap0[g].u = uint32x4{pk[g][0], pk[g][1], pk[g][2], pk[g][3]};
      ap1[g].u = uint32x4{pk[g][4], pk[g][5], pk[g][6], pk[g][7]};
    }

    bf16x8 mr0 = *(const bf16x8*)(Ml + kt * 64 + quad * 8);
    bf16x8 mr1 = *(const bf16x8*)(Ml + kt * 64 + 32 + quad * 8);
    if (l16 != 0) { mr0 = zfrag; mr1 = zfrag; }
#pragma unroll
    for (int g = 0; g < 2; ++g) {
      dacc[g] = __builtin_amdgcn_mfma_f32_16x16x32_bf16(ap0[g].h, mr0, dacc[g], 0, 0, 0);
      dacc[g] = __builtin_amdgcn_mfma_f32_16x16x32_bf16(ap1[g].h, mr1, dacc[g], 0, 0, 0);
    }

#pragma unroll
    for (int d = 0; d < 4; ++d) {
      const int row = d * 16 + l16;
      const int sw = SW(row);
      bf16x8 bv0 = *(const bf16x8*)(Vt[cur] + row * 64 + (quad ^ sw) * 8);
      bf16x8 bv1 = *(const bf16x8*)(Vt[cur] + row * 64 + ((quad + 4) ^ sw) * 8);
#pragma unroll
      for (int g = 0; g < 2; ++g) {
        acc[g][d] = __builtin_amdgcn_mfma_f32_16x16x32_bf16(ap0[g].h, bv0, acc[g][d], 0, 0, 0);
        acc[g][d] = __builtin_amdgcn_mfma_f32_16x16x32_bf16(ap1[g].h, bv1, acc[g][d], 0, 0, 0);
      }
    }

    __syncthreads();
  }

#pragma unroll
  for (int g = 0; g < 2; ++g) {
    const size_t obase = (size_t)(b * Ssz + qt * 128 + g * 64 + wave * 16 + quad * 4) * HID + h * DKc + l16;
#pragma unroll
    for (int r = 0; r < 4; ++r) {
      const float denom = __shfl(dacc[g][r], lane & 48, 64);
      const float rl = 1.f / denom;
#pragma unroll
      for (int d = 0; d < 4; ++d)
        cv[obase + (size_t)r * HID + d * 16] = (bf16_t)(acc[g][d][r] * rl);
    }
  }
}

// ---------------- host ----------------
extern "C" void kernel_launch(void* const* d_in, const int* in_sizes, int n_in,
                              void* d_out, int out_size, void* d_ws, size_t ws_size,
                              hipStream_t stream) {
  (void)in_sizes; (void)n_in; (void)out_size; (void)ws_size;
  const float* q_in = (const float*)d_in[0];
  const float* k_in = (const float*)d_in[1];
  const float* v_in = (const float*)d_in[2];
  const int* mask = (const int*)d_in[3];

  bf16_t* XB = (bf16_t*)d_ws;                          // 3 slots [8192,1024] bf16: q, k, V^T
  bf16_t* H3 = XB + (size_t)3 * Mrows * HID;           // 3 x [8192,256] bf16
  bf16_t* CV = H3 + (size_t)3 * Mrows * FAC;           // [8192,1024] bf16 (masked V, then attn out)
  bf16_t* WPT = CV + (size_t)Mrows * HID;              // 4 x [256,1024] bf16
  bf16_t* WTT = WPT + (size_t)4 * FAC * HID;           // 4 x [1024,256] bf16
  float* BP = (float*)(WTT + (size_t)4 * FAC * HID);   // 4 x 256 f32
  float* BT = BP + 4 * FAC;                            // 4 x 1024 f32
  float* MF = BT + 4 * HID;                            // [8192] f32 mask rowmul
  bf16_t* MB = (bf16_t*)(MF + Mrows);                  // [8192] bf16 mask row
  bf16_t* VTg = XB + 2 * (size_t)Mrows * HID;

  Ptr8 w;
  w.p[0] = (const float*)d_in[4];  w.p[1] = (const float*)d_in[8];
  w.p[2] = (const float*)d_in[12]; w.p[3] = (const float*)d_in[16];
  w.p[4] = (const float*)d_in[6];  w.p[5] = (const float*)d_in[10];
  w.p[6] = (const float*)d_in[14]; w.p[7] = (const float*)d_in[18];
  hipLaunchKernelGGL(k_prep_w, dim3(32, 32, 8), dim3(256), 0, stream, w, WPT, WTT);

  Ptr8 bs;
  bs.p[0] = (const float*)d_in[5];  bs.p[1] = (const float*)d_in[9];
  bs.p[2] = (const float*)d_in[13]; bs.p[3] = (const float*)d_in[17];
  bs.p[4] = (const float*)d_in[7];  bs.p[5] = (const float*)d_in[11];
  bs.p[6] = (const float*)d_in[15]; bs.p[7] = (const float*)d_in[19];
  hipLaunchKernelGGL(k_pack_bias, dim3(64), dim3(256), 0, stream, bs, mask, BP, BT, MF, MB);

  Ptr3 xs; xs.p[0] = q_in; xs.p[1] = k_in; xs.p[2] = v_in;
  Ptr3 nullp; nullp.p[0] = nullp.p[1] = nullp.p[2] = nullptr;

  // proj q,k,v: fp32 A (cast fused) @ WPT^T + b -> leaky -> H3   [64x128 tiles, dbuf]
  hipLaunchKernelGGL((k_gemmP<1, bf16_t>), dim3(2, Mrows / 64, 3), dim3(256), 0, stream,
                     xs, (const bf16_t*)nullptr, WPT, BP, H3,
                     HID, 0LL, (long long)FAC * HID, (long long)Mrows * FAC, FAC);

  // tran q,k,v: H3 @ WTT^T + b -> q,k into XB; v (mask-multiplied rows) into CV
  hipLaunchKernelGGL((k_gemm<0, 1, bf16_t>), dim3(HID / 128, Mrows / 128, 3), dim3(256), 0, stream,
                     H3, WTT, BT, XB, CV, MF,
                     HID, FAC, (long long)Mrows * FAC, (long long)FAC * HID, (long long)Mrows * HID, HID,
                     QSCALE, 1.f, 1.f);

  // transpose masked V: CV -> VTg ([b,h,d,s])
  hipLaunchKernelGGL(k_tv, dim3(Ssz / 64, NH, Bsz), dim3(256), 0, stream, CV, VTg);

  // attention -> CV (128 q-rows per block)
  hipLaunchKernelGGL(k_attn, dim3(Ssz / 128, NH, Bsz), dim3(256), 0, stream, XB, MB, CV);

  // proj o: CV @ WPT[o]^T + b -> leaky -> H3[0]   [64x128 tiles, dbuf]
  hipLaunchKernelGGL((k_gemmP<0, bf16_t>), dim3(2, Mrows / 64, 1), dim3(256), 0, stream,
                     nullp, CV, WPT + (size_t)3 * FAC * HID, BP + 3 * FAC, H3,
                     HID, 0LL, 0LL, 0LL, 0);

  // tran o: H3 @ WTT[o]^T + b -> d_out (fp32)
  hipLaunchKernelGGL((k_gemm<0, 0, float>), dim3(HID / 128, Mrows / 128, 1), dim3(256), 0, stream,
                     H3, WTT + (size_t)3 * FAC * HID, BT + 3 * HID, (float*)d_out, (float*)nullptr,
                     (const float*)nullptr, HID, FAC, 0LL, 0LL, 0LL, 0, 1.f, 1.f, 1.f);
}

// Round 6
// 344.197 us; speedup vs baseline: 2.2191x; 1.0273x over previous
//
#include <hip/hip_runtime.h>
#include <cstdint>
#include <cstddef>

typedef __bf16 bf16_t;
typedef __bf16 bf16x8 __attribute__((ext_vector_type(8)));
typedef float  f32x4  __attribute__((ext_vector_type(4)));
typedef unsigned int uint32x4 __attribute__((ext_vector_type(4)));
typedef unsigned int uint32x2 __attribute__((ext_vector_type(2)));

#define DEV_INLINE __device__ __forceinline__

constexpr int Bsz = 4, Ssz = 2048, HID = 1024, FAC = 256, NH = 16, DKc = 64;
constexpr int Mrows = Bsz * Ssz; // 8192
constexpr float QSCALE = 0.18033688011112042f; // (1/sqrt(64)) * log2(e)

struct Ptr8 { const float* p[8]; };
struct Ptr3 { const float* p[3]; };

DEV_INLINE float fast_exp2(float x) {
#if __has_builtin(__builtin_amdgcn_exp2f)
  return __builtin_amdgcn_exp2f(x);
#else
  return exp2f(x);
#endif
}

// async global->LDS, 16 B per lane. LDS dest is wave-uniform base + lane*16.
DEV_INLINE void async16(const void* g, void* l) {
  __builtin_amdgcn_global_load_lds((const __attribute__((address_space(1))) void*)g,
                                   (__attribute__((address_space(3))) void*)l, 16, 0, 0);
}

// bank swizzle for [64][64] bf16 tiles staged by global_load_lds:
// LDS[row][c'] holds logical col16 (c' ^ SW(row)). Readers XOR too.
DEV_INLINE int SW(int r) { return (r & 3) | ((r >> 1) & 4); }

// ---------------- prep: weight transpose+cast (z<8) + bias/mask pack (z==8) ----------------
__global__ __launch_bounds__(256) void k_prep(Ptr8 w, Ptr8 bsrc, const int* __restrict__ mask,
                                              bf16_t* wpt, bf16_t* wtt,
                                              float* bp, float* bt, float* mf, bf16_t* mb) {
  const int z = blockIdx.z;
  if (z == 8) {
    const int bid = blockIdx.y * 32 + blockIdx.x;
    if (bid >= 64) return;
    const int i = bid * 256 + threadIdx.x; // 0..16383
    if (i < 4 * FAC) bp[i] = bsrc.p[i >> 8][i & 255];
    if (i < 4 * HID) bt[i] = bsrc.p[4 + (i >> 10)][i & 1023];
    if (i < Bsz * Ssz) {
      const float m = (mask[i] != 0) ? 1.f : 0.f;
      mf[i] = m;
      mb[i] = (bf16_t)m;
    }
    return;
  }
  const int K = (z < 4) ? HID : FAC;
  const int N = (z < 4) ? FAC : HID;
  if ((int)(blockIdx.x * 32) >= N || (int)(blockIdx.y * 32) >= K) return;
  __shared__ float t[32][33];
  const float* src = w.p[z];
  bf16_t* dst = (z < 4) ? (wpt + (size_t)z * FAC * HID) : (wtt + (size_t)(z - 4) * FAC * HID);
  const int tx = threadIdx.x & 31, ty = threadIdx.x >> 5;
  const int kb = blockIdx.y * 32, nb = blockIdx.x * 32;
#pragma unroll
  for (int j = 0; j < 4; ++j)
    t[ty + j * 8][tx] = src[(size_t)(kb + ty + j * 8) * N + nb + tx];
  __syncthreads();
#pragma unroll
  for (int j = 0; j < 4; ++j)
    dst[(size_t)(nb + ty + j * 8) * K + kb + tx] = (bf16_t)t[tx][ty + j * 8];
}

// ---------------- proj GEMM: C[M,256] = leaky(A[M,K] @ Bt[256,K]^T + bias) ----------------
// 64x128 tile, BK=32, 4 waves (each 64x32), double-buffered LDS, ONE barrier per K-iter.
template <int CAST_A, typename OUT_T>
__global__ __launch_bounds__(256) void k_gemmP(Ptr3 Asrc,
                                               const bf16_t* __restrict__ Aall,
                                               const bf16_t* __restrict__ Bt_,
                                               const float* __restrict__ biasAll,
                                               OUT_T* __restrict__ Call,
                                               int K,
                                               long long Az, long long Bz, long long Cz, int biasz) {
  constexpr int LDTA = CAST_A ? 40 : 32;
  __shared__ __align__(16) bf16_t As[2][64 * LDTA];
  __shared__ __align__(16) bf16_t Bs[2][128 * 32];

  const int z = blockIdx.z;
  const bf16_t* Bt = Bt_ + (size_t)z * Bz;
  const float* bias = biasAll + (size_t)z * biasz;
  OUT_T* C = Call + (size_t)z * Cz;

  const int tid = threadIdx.x;
  const int lane = tid & 63, wave = tid >> 6;
  const int quad = lane >> 4, l16 = lane & 15;
  const int m0 = blockIdx.y * 64, n0 = blockIdx.x * 128;

  const int arow = wave * 16 + (lane >> 2), akc = (lane & 3) * 8;
  const bf16_t* gB0 = Bt + (size_t)(n0 + arow) * K + akc;
  const bf16_t* gB1 = gB0 + (size_t)64 * K;

  const float* gAf = nullptr;
  const bf16_t* gA = nullptr;
  const int crow = tid >> 2, chalf = (tid & 3) * 8;
  if (CAST_A) gAf = Asrc.p[z] + (size_t)(m0 + crow) * K + chalf;
  else        gA  = Aall + (size_t)z * Az + (size_t)(m0 + arow) * K + akc;

  // prologue: stage k0=0 into buffer 0
  async16(gB0, Bs[0] + wave * 512);
  async16(gB1, Bs[0] + 2048 + wave * 512);
  if (CAST_A) {
    f32x4 x0 = *(const f32x4*)gAf;
    f32x4 x1 = *(const f32x4*)(gAf + 4);
    union { bf16_t h[8]; uint32x4 u; } o;
#pragma unroll
    for (int j = 0; j < 4; ++j) { o.h[j] = (bf16_t)x0[j]; o.h[4 + j] = (bf16_t)x1[j]; }
    *(uint32x4*)(As[0] + crow * LDTA + chalf) = o.u;
  } else {
    async16(gA, As[0] + wave * 512);
  }

  f32x4 acc[4][2] = {};
  const int nk = K / 32;

  for (int it = 0; it < nk; ++it) {
    const int cur = it & 1, nxt = cur ^ 1;
    __syncthreads();

    f32x4 xa, xb;
    const int k1 = (it + 1) * 32;
    if (it + 1 < nk) {
      async16(gB0 + k1, Bs[nxt] + wave * 512);
      async16(gB1 + k1, Bs[nxt] + 2048 + wave * 512);
      if (CAST_A) {
        xa = *(const f32x4*)(gAf + k1);
        xb = *(const f32x4*)(gAf + k1 + 4);
      } else {
        async16(gA + k1, As[nxt] + wave * 512);
      }
    }

    bf16x8 af[4], bfr[2];
#pragma unroll
    for (int i = 0; i < 4; ++i)
      af[i] = *(const bf16x8*)(As[cur] + (i * 16 + l16) * LDTA + quad * 8);
#pragma unroll
    for (int i = 0; i < 2; ++i)
      bfr[i] = *(const bf16x8*)(Bs[cur] + (wave * 32 + i * 16 + l16) * 32 + quad * 8);
#pragma unroll
    for (int mi = 0; mi < 4; ++mi)
#pragma unroll
      for (int ni = 0; ni < 2; ++ni)
        acc[mi][ni] = __builtin_amdgcn_mfma_f32_16x16x32_bf16(af[mi], bfr[ni], acc[mi][ni], 0, 0, 0);

    if (CAST_A && it + 1 < nk) {
      union { bf16_t h[8]; uint32x4 u; } o;
#pragma unroll
      for (int j = 0; j < 4; ++j) { o.h[j] = (bf16_t)xa[j]; o.h[4 + j] = (bf16_t)xb[j]; }
      *(uint32x4*)(As[nxt] + crow * LDTA + chalf) = o.u;
    }
  }

#pragma unroll
  for (int mi = 0; mi < 4; ++mi) {
    const int rbase = m0 + mi * 16 + quad * 4;
#pragma unroll
    for (int ni = 0; ni < 2; ++ni) {
      const int col = n0 + wave * 32 + ni * 16 + l16;
      const float bv = bias[col];
#pragma unroll
      for (int r = 0; r < 4; ++r) {
        float y = acc[mi][ni][r] + bv;
        y = (y > 0.f) ? y : 0.2f * y;
        C[(size_t)(rbase + r) * FAC + col] = (OUT_T)y;
      }
    }
  }
}

// ---------------- tran GEMM: C[M,N] = (A[M,K] @ Bt[N,K]^T + bias) * scale ----------------
// TVW=1: z==2 writes masked V DIRECTLY TRANSPOSED into C2 ([b,h,d,s] layout), fusing k_tv.
template <int TVW, typename OUT_T>
__global__ __launch_bounds__(256) void k_gemm(const bf16_t* __restrict__ Aall,
                                              const bf16_t* __restrict__ Btall,
                                              const float* __restrict__ biasAll,
                                              OUT_T* __restrict__ Call,
                                              bf16_t* __restrict__ C2,
                                              const float* __restrict__ rowmul,
                                              int N, int K,
                                              long long Az, long long Bz, long long Cz, int biasz,
                                              float sc0, float sc1) {
  __shared__ __align__(16) bf16_t As[128 * 32];
  __shared__ __align__(16) bf16_t Bs[128 * 32];

  const int z = blockIdx.z;
  const bf16_t* Bt = Btall + (size_t)z * Bz;
  const float* bias = biasAll + (size_t)z * biasz;
  OUT_T* C = Call + (size_t)z * Cz;
  const float scale = (z == 0) ? sc0 : sc1;

  const int tid = threadIdx.x;
  const int lane = tid & 63, wave = tid >> 6;
  const int quad = lane >> 4, l16 = lane & 15;
  const int wr = wave >> 1, wc = wave & 1;
  const int m0 = blockIdx.y * 128, n0 = blockIdx.x * 128;

  const int arow = wave * 16 + (lane >> 2), akc = (lane & 3) * 8;
  const bf16_t* gB0 = Bt + (size_t)(n0 + arow) * K + akc;
  const bf16_t* gB1 = gB0 + (size_t)64 * K;
  bf16_t* lB0 = Bs + wave * 512;
  bf16_t* lB1 = Bs + 2048 + wave * 512;

  const bf16_t* A = Aall + (size_t)z * Az;
  const bf16_t* gA0 = A + (size_t)(m0 + arow) * K + akc;
  const bf16_t* gA1 = gA0 + (size_t)64 * K;
  bf16_t* lA0 = As + wave * 512;
  bf16_t* lA1 = As + 2048 + wave * 512;

  f32x4 acc[4][4] = {};

  for (int k0 = 0; k0 < K; k0 += 32) {
    async16(gB0 + k0, lB0);
    async16(gB1 + k0, lB1);
    async16(gA0 + k0, lA0);
    async16(gA1 + k0, lA1);
    __syncthreads();

    bf16x8 af[4], bfr[4];
#pragma unroll
    for (int i = 0; i < 4; ++i)
      af[i] = *(const bf16x8*)(As + (wr * 64 + i * 16 + l16) * 32 + quad * 8);
#pragma unroll
    for (int i = 0; i < 4; ++i)
      bfr[i] = *(const bf16x8*)(Bs + (wc * 64 + i * 16 + l16) * 32 + quad * 8);
#pragma unroll
    for (int mi = 0; mi < 4; ++mi)
#pragma unroll
      for (int ni = 0; ni < 4; ++ni)
        acc[mi][ni] = __builtin_amdgcn_mfma_f32_16x16x32_bf16(af[mi], bfr[ni], acc[mi][ni], 0, 0, 0);
    if (k0 + 32 < K) __syncthreads();
  }

  if (TVW && z == 2) {
    // transposed masked write: V^T[(b*NH+h)*64+d][s] = (acc + bias) * mask[s]
#pragma unroll
    for (int mi = 0; mi < 4; ++mi) {
      const int rbase = m0 + wr * 64 + mi * 16 + quad * 4;
      const int bb = rbase >> 11, s = rbase & 2047;
      float rmv[4];
#pragma unroll
      for (int r = 0; r < 4; ++r) rmv[r] = rowmul[rbase + r];
#pragma unroll
      for (int ni = 0; ni < 4; ++ni) {
        const int col = n0 + wc * 64 + ni * 16 + l16;
        const float bv = bias[col];
        const int h = col >> 6, d = col & 63;
        union { bf16_t e[4]; uint32x2 u; } p;
#pragma unroll
        for (int r = 0; r < 4; ++r) p.e[r] = (bf16_t)((acc[mi][ni][r] + bv) * rmv[r]);
        *(uint32x2*)(C2 + (((size_t)((bb * NH + h) * DKc + d)) << 11) + s) = p.u;
      }
    }
    return;
  }

#pragma unroll
  for (int mi = 0; mi < 4; ++mi) {
    const int rbase = m0 + wr * 64 + mi * 16 + quad * 4;
#pragma unroll
    for (int ni = 0; ni < 4; ++ni) {
      const int col = n0 + wc * 64 + ni * 16 + l16;
      const float bv = bias[col];
#pragma unroll
      for (int r = 0; r < 4; ++r) {
        float y = (acc[mi][ni][r] + bv) * scale;
        C[(size_t)(rbase + r) * N + col] = (OUT_T)y;
      }
    }
  }
}

// ---------------- flash attention v5: 256 q-rows/block (4 groups of 64) ----------------
// K/V frag LDS reads + DMA bytes amortized over 4 q-groups -> MFMA-bound, not LDS-bound.
__global__ __launch_bounds__(256, 2) void k_attn(const bf16_t* __restrict__ qkv,
                                                 const bf16_t* __restrict__ mb,
                                                 bf16_t* __restrict__ cv) {
  __shared__ __align__(16) bf16_t Ks[2][64 * 64];
  __shared__ __align__(16) bf16_t Vt[2][64 * 64];
  __shared__ __align__(16) bf16_t Ml[Ssz];

  const int qt = blockIdx.x, h = blockIdx.y, b = blockIdx.z;
  const bf16_t* qp = qkv;
  const bf16_t* kp = qkv + (size_t)Mrows * HID;
  const bf16_t* vtp = qkv + 2 * (size_t)Mrows * HID + (size_t)(b * NH + h) * DKc * Ssz;

  const int tid = threadIdx.x;
  const int lane = tid & 63, wave = tid >> 6;
  const int quad = lane >> 4, l16 = lane & 15;

  const int r0 = wave * 16 + (lane >> 3);
  const int r1 = r0 + 8;
  const int c0 = ((lane & 7) ^ SW(r0)) * 8;
  const int c1 = ((lane & 7) ^ SW(r1)) * 8;
  const int ldsOff = wave * 1024;
  const bf16_t* kgA = kp + (size_t)(b * Ssz + r0) * HID + h * DKc + c0;
  const bf16_t* kgB = kp + (size_t)(b * Ssz + r1) * HID + h * DKc + c1;
  const bf16_t* vgA = vtp + (size_t)r0 * Ssz + c0;
  const bf16_t* vgB = vtp + (size_t)r1 * Ssz + c1;

  *(uint32x4*)(Ml + tid * 8) = *(const uint32x4*)(mb + (size_t)b * Ssz + tid * 8);
  async16(kgA, Ks[0] + ldsOff);
  async16(kgB, Ks[0] + ldsOff + 512);
  async16(vgA, Vt[0] + ldsOff);
  async16(vgB, Vt[0] + ldsOff + 512);

  bf16x8 aq0[4], aq1[4];
#pragma unroll
  for (int g = 0; g < 4; ++g) {
    const size_t qrow = (size_t)(b * Ssz + qt * 256 + g * 64 + wave * 16 + l16) * HID + h * DKc + quad * 8;
    aq0[g] = *(const bf16x8*)(qp + qrow);
    aq1[g] = *(const bf16x8*)(qp + qrow + 32);
  }
  __syncthreads();

  const int krow = 8 * (l16 >> 2) + (l16 & 3);
  f32x4 acc[4][4] = {};
  f32x4 dacc[4] = {};
  const bf16x8 zfrag = {};

  for (int kt = 0; kt < 32; ++kt) {
    const int cur = kt & 1, nxt = cur ^ 1;
    if (kt < 31) {
      const size_t ko = (size_t)(kt + 1) * 64 * HID;
      const int vo = (kt + 1) * 64;
      async16(kgA + ko, Ks[nxt] + ldsOff);
      async16(kgB + ko, Ks[nxt] + ldsOff + 512);
      async16(vgA + vo, Vt[nxt] + ldsOff);
      async16(vgB + vo, Vt[nxt] + ldsOff + 512);
    }

    union U { uint32x4 u; bf16x8 h; } ap0[4], ap1[4];
    constexpr int koff[4] = {0, 4, 32, 36};
#pragma unroll
    for (int ks = 0; ks < 4; ++ks) {
      const int row = krow + koff[ks];
      const int sw = SW(row);
      bf16x8 a0 = *(const bf16x8*)(Ks[cur] + row * 64 + (quad ^ sw) * 8);
      bf16x8 a1 = *(const bf16x8*)(Ks[cur] + row * 64 + ((quad + 4) ^ sw) * 8);
#pragma unroll
      for (int g = 0; g < 4; ++g) {
        f32x4 c = {};
        c = __builtin_amdgcn_mfma_f32_16x16x32_bf16(a0, aq0[g], c, 0, 0, 0);
        c = __builtin_amdgcn_mfma_f32_16x16x32_bf16(a1, aq1[g], c, 0, 0, 0);
        union { bf16_t h[2]; uint32_t u; } p01, p23;
        p01.h[0] = (bf16_t)fast_exp2(c[0]);
        p01.h[1] = (bf16_t)fast_exp2(c[1]);
        p23.h[0] = (bf16_t)fast_exp2(c[2]);
        p23.h[1] = (bf16_t)fast_exp2(c[3]);
        U& t = (ks < 2) ? ap0[g] : ap1[g];
        t.u[(ks & 1) * 2] = p01.u;
        t.u[(ks & 1) * 2 + 1] = p23.u;
      }
    }

    bf16x8 mr0 = *(const bf16x8*)(Ml + kt * 64 + quad * 8);
    bf16x8 mr1 = *(const bf16x8*)(Ml + kt * 64 + 32 + quad * 8);
    if (l16 != 0) { mr0 = zfrag; mr1 = zfrag; }
#pragma unroll
    for (int g = 0; g < 4; ++g) {
      dacc[g] = __builtin_amdgcn_mfma_f32_16x16x32_bf16(ap0[g].h, mr0, dacc[g], 0, 0, 0);
      dacc[g] = __builtin_amdgcn_mfma_f32_16x16x32_bf16(ap1[g].h, mr1, dacc[g], 0, 0, 0);
    }

#pragma unroll
    for (int d = 0; d < 4; ++d) {
      const int row = d * 16 + l16;
      const int sw = SW(row);
      bf16x8 bv0 = *(const bf16x8*)(Vt[cur] + row * 64 + (quad ^ sw) * 8);
      bf16x8 bv1 = *(const bf16x8*)(Vt[cur] + row * 64 + ((quad + 4) ^ sw) * 8);
#pragma unroll
      for (int g = 0; g < 4; ++g) {
        acc[g][d] = __builtin_amdgcn_mfma_f32_16x16x32_bf16(ap0[g].h, bv0, acc[g][d], 0, 0, 0);
        acc[g][d] = __builtin_amdgcn_mfma_f32_16x16x32_bf16(ap1[g].h, bv1, acc[g][d], 0, 0, 0);
      }
    }

    __syncthreads();
  }

#pragma unroll
  for (int g = 0; g < 4; ++g) {
    const size_t obase = (size_t)(b * Ssz + qt * 256 + g * 64 + wave * 16 + quad * 4) * HID + h * DKc + l16;
#pragma unroll
    for (int r = 0; r < 4; ++r) {
      const float denom = __shfl(dacc[g][r], lane & 48, 64);
      const float rl = 1.f / denom;
#pragma unroll
      for (int d = 0; d < 4; ++d)
        cv[obase + (size_t)r * HID + d * 16] = (bf16_t)(acc[g][d][r] * rl);
    }
  }
}

// ---------------- host ----------------
extern "C" void kernel_launch(void* const* d_in, const int* in_sizes, int n_in,
                              void* d_out, int out_size, void* d_ws, size_t ws_size,
                              hipStream_t stream) {
  (void)in_sizes; (void)n_in; (void)out_size; (void)ws_size;
  const float* q_in = (const float*)d_in[0];
  const float* k_in = (const float*)d_in[1];
  const float* v_in = (const float*)d_in[2];
  const int* mask = (const int*)d_in[3];

  bf16_t* XB = (bf16_t*)d_ws;                          // 3 slots [8192,1024] bf16: q, k, V^T
  bf16_t* H3 = XB + (size_t)3 * Mrows * HID;           // 3 x [8192,256] bf16
  bf16_t* CV = H3 + (size_t)3 * Mrows * FAC;           // [8192,1024] bf16 (attn out)
  bf16_t* WPT = CV + (size_t)Mrows * HID;              // 4 x [256,1024] bf16
  bf16_t* WTT = WPT + (size_t)4 * FAC * HID;           // 4 x [1024,256] bf16
  float* BP = (float*)(WTT + (size_t)4 * FAC * HID);   // 4 x 256 f32
  float* BT = BP + 4 * FAC;                            // 4 x 1024 f32
  float* MF = BT + 4 * HID;                            // [8192] f32 mask rowmul
  bf16_t* MB = (bf16_t*)(MF + Mrows);                  // [8192] bf16 mask row
  bf16_t* VTg = XB + 2 * (size_t)Mrows * HID;          // V^T slot

  Ptr8 w;
  w.p[0] = (const float*)d_in[4];  w.p[1] = (const float*)d_in[8];
  w.p[2] = (const float*)d_in[12]; w.p[3] = (const float*)d_in[16];
  w.p[4] = (const float*)d_in[6];  w.p[5] = (const float*)d_in[10];
  w.p[6] = (const float*)d_in[14]; w.p[7] = (const float*)d_in[18];
  Ptr8 bs;
  bs.p[0] = (const float*)d_in[5];  bs.p[1] = (const float*)d_in[9];
  bs.p[2] = (const float*)d_in[13]; bs.p[3] = (const float*)d_in[17];
  bs.p[4] = (const float*)d_in[7];  bs.p[5] = (const float*)d_in[11];
  bs.p[6] = (const float*)d_in[15]; bs.p[7] = (const float*)d_in[19];
  hipLaunchKernelGGL(k_prep, dim3(32, 32, 9), dim3(256), 0, stream, w, bs, mask,
                     WPT, WTT, BP, BT, MF, MB);

  Ptr3 xs; xs.p[0] = q_in; xs.p[1] = k_in; xs.p[2] = v_in;
  Ptr3 nullp; nullp.p[0] = nullp.p[1] = nullp.p[2] = nullptr;

  // proj q,k,v: fp32 A (cast fused) @ WPT^T + b -> leaky -> H3   [64x128 tiles, dbuf]
  hipLaunchKernelGGL((k_gemmP<1, bf16_t>), dim3(2, Mrows / 64, 3), dim3(256), 0, stream,
                     xs, (const bf16_t*)nullptr, WPT, BP, H3,
                     HID, 0LL, (long long)FAC * HID, (long long)Mrows * FAC, FAC);

  // tran q,k,v: H3 @ WTT^T + b -> q,k into XB; v masked+TRANSPOSED into VTg (k_tv fused)
  hipLaunchKernelGGL((k_gemm<1, bf16_t>), dim3(HID / 128, Mrows / 128, 3), dim3(256), 0, stream,
                     H3, WTT, BT, XB, VTg, MF,
                     HID, FAC, (long long)Mrows * FAC, (long long)FAC * HID, (long long)Mrows * HID, HID,
                     QSCALE, 1.f);

  // attention -> CV (256 q-rows per block)
  hipLaunchKernelGGL(k_attn, dim3(Ssz / 256, NH, Bsz), dim3(256), 0, stream, XB, MB, CV);

  // proj o: CV @ WPT[o]^T + b -> leaky -> H3[0]   [64x128 tiles, dbuf]
  hipLaunchKernelGGL((k_gemmP<0, bf16_t>), dim3(2, Mrows / 64, 1), dim3(256), 0, stream,
                     nullp, CV, WPT + (size_t)3 * FAC * HID, BP + 3 * FAC, H3,
                     HID, 0LL, 0LL, 0LL, 0);

  // tran o: H3 @ WTT[o]^T + b -> d_out (fp32)
  hipLaunchKernelGGL((k_gemm<0, float>), dim3(HID / 128, Mrows / 128, 1), dim3(256), 0, stream,
                     H3, WTT + (size_t)3 * FAC * HID, BT + 3 * HID, (float*)d_out, (bf16_t*)nullptr,
                     (const float*)nullptr, HID, FAC, 0LL, 0LL, 0LL, 0, 1.f, 1.f);
}